// Round 2
// baseline (306.853 us; speedup 1.0000x reference)
//
#include <hip/hip_runtime.h>
#include <math.h>

#define BB 16
#define SS 256
#define FF 512
#define EE 128
#define HH 64
#define GG 192  // 3H
#define LL 8

__device__ __forceinline__ float sigmoid_f(float x) {
    return 1.0f / (1.0f + __expf(-x));
}
__device__ __forceinline__ float tanh_f(float x) {
    // 1 - 2/(1+e^{2x}): saturates cleanly to ±1, no NaN for large |x|
    return 1.0f - 2.0f / (1.0f + __expf(2.0f * x));
}

// ---------------------------------------------------------------------------
// Generic C[m,n] = sum_k A[m,k] * Bm[n,k] + bias[n]
// Tile: 32 rows x 64 cols, K chunks of 64. Block = 256 threads.
// Requires M % 32 == 0, K % 64 == 0. N handled with guards (launch gy = ceil).
// ---------------------------------------------------------------------------
__global__ __launch_bounds__(256) void gemm_bt(
    const float* __restrict__ A, const float* __restrict__ Bm,
    const float* __restrict__ bias, float* __restrict__ C,
    int N, int K)
{
    __shared__ float As[32][68];
    __shared__ float Bs[64][68];
    const int t = threadIdx.x;
    const int row0 = blockIdx.x * 32;
    const int col0 = blockIdx.y * 64;
    const int tr = t & 7;        // 0..7 row-group
    const int tc = t >> 3;       // 0..31 col-group
    float acc[4][2] = {{0.f,0.f},{0.f,0.f},{0.f,0.f},{0.f,0.f}};

    for (int k0 = 0; k0 < K; k0 += 64) {
        // A tile: 32 rows x 64 k. lane: row = t>>3, quad = t&7 (+8)
        {
            int r = t >> 3;          // 0..31
            int q = t & 7;           // 0..7
            const float* src = &A[(size_t)(row0 + r) * K + k0];
            #pragma unroll
            for (int it = 0; it < 2; ++it) {
                int kk = (q + it * 8) * 4;
                *(float4*)&As[r][kk] = *(const float4*)&src[kk];
            }
        }
        // B tile: 64 rows x 64 k. lane: row = t>>2, quad = t&3 (+4,+8,+12)
        {
            int r = t >> 2;          // 0..63
            int q = t & 3;           // 0..3
            int n = col0 + r;
            #pragma unroll
            for (int it = 0; it < 4; ++it) {
                int kk = (q + it * 4) * 4;
                float4 v = {0.f, 0.f, 0.f, 0.f};
                if (n < N) v = *(const float4*)&Bm[(size_t)n * K + k0 + kk];
                *(float4*)&Bs[r][kk] = v;
            }
        }
        __syncthreads();
        #pragma unroll
        for (int k = 0; k < 64; k += 4) {
            float4 av[4], bv[2];
            #pragma unroll
            for (int i = 0; i < 4; ++i) av[i] = *(const float4*)&As[tr + 8*i][k];
            #pragma unroll
            for (int j = 0; j < 2; ++j) bv[j] = *(const float4*)&Bs[tc + 32*j][k];
            #pragma unroll
            for (int i = 0; i < 4; ++i)
                #pragma unroll
                for (int j = 0; j < 2; ++j)
                    acc[i][j] += av[i].x*bv[j].x + av[i].y*bv[j].y
                               + av[i].z*bv[j].z + av[i].w*bv[j].w;
        }
        __syncthreads();
    }

    #pragma unroll
    for (int i = 0; i < 4; ++i) {
        int r = row0 + tr + 8*i;
        #pragma unroll
        for (int j = 0; j < 2; ++j) {
            int c = col0 + tc + 32*j;
            if (c < N) C[(size_t)r * N + c] = acc[i][j] + bias[c];
        }
    }
}

// ---------------------------------------------------------------------------
// GRU scan, latency-optimized. ONE WAVE per (batch, which-gru) chain:
// grid 32 blocks x 64 threads. Lane j holds the three Whh rows (j, j+64,
// j+128) in 192 VGPRs and owns h[j] in a register. The h-broadcast for the
// matvec is v_readlane (SGPR), consumed directly by v_fma. No LDS, no
// barriers in the recurrence. xp for step s+1 prefetched during step s.
// ---------------------------------------------------------------------------
__global__ __launch_bounds__(64, 1) void gru_kernel(
    const float* __restrict__ xpa, const float* __restrict__ xpb,
    const float* __restrict__ Whh_a, const float* __restrict__ bhh_a,
    const float* __restrict__ Whh_b, const float* __restrict__ bhh_b,
    float* __restrict__ hs_a, float* __restrict__ hs_b)
{
    const int blk = blockIdx.x;      // 0..31
    const int b = blk >> 1;
    const int which = blk & 1;
    const float* xp  = which ? xpb   : xpa;
    const float* Whh = which ? Whh_b : Whh_a;
    const float* bhh = which ? bhh_b : bhh_a;
    float* hs        = which ? hs_b  : hs_a;

    const int j = threadIdx.x;       // 0..63

    // Load lane-private weight rows into VGPRs (one-time, 48 KB per block).
    float wr[64], wz[64], wn[64];
    {
        const float4* r0 = (const float4*)&Whh[(size_t)j * HH];
        const float4* r1 = (const float4*)&Whh[(size_t)(j + 64) * HH];
        const float4* r2 = (const float4*)&Whh[(size_t)(j + 128) * HH];
        #pragma unroll
        for (int k = 0; k < 16; ++k) {
            float4 v0 = r0[k], v1 = r1[k], v2 = r2[k];
            wr[4*k] = v0.x; wr[4*k+1] = v0.y; wr[4*k+2] = v0.z; wr[4*k+3] = v0.w;
            wz[4*k] = v1.x; wz[4*k+1] = v1.y; wz[4*k+2] = v1.z; wz[4*k+3] = v1.w;
            wn[4*k] = v2.x; wn[4*k+1] = v2.y; wn[4*k+2] = v2.z; wn[4*k+3] = v2.w;
        }
    }
    const float br = bhh[j], bz = bhh[j + 64], bn = bhh[j + 128];

    const float* xrow = xp + (size_t)b * SS * GG;
    float* hrow = hs + (size_t)b * SS * HH;
    float hcur = 0.f;

    // prefetch step 0
    float xr = xrow[j], xz = xrow[j + 64], xn = xrow[j + 128];

    for (int s = 0; s < SS; ++s) {
        // Prefetch next step's xp (last iter reads 192 floats past this xp
        // array; that lands in the adjacent workspace region — safe, unused).
        const float* nx = xrow + GG;
        float nxr = nx[j], nxz = nx[j + 64], nxn = nx[j + 128];

        float ar = br, az = bz, an = bn;
        #pragma unroll
        for (int k = 0; k < 64; ++k) {
            float hk = __int_as_float(__builtin_amdgcn_readlane(__float_as_int(hcur), k));
            ar = fmaf(wr[k], hk, ar);
            az = fmaf(wz[k], hk, az);
            an = fmaf(wn[k], hk, an);
        }
        float r = sigmoid_f(xr + ar);
        float z = sigmoid_f(xz + az);
        float n = tanh_f(xn + r * an);
        hcur = fmaf(z, hcur - n, n);   // (1-z)*n + z*h
        hrow[j] = hcur;

        xr = nxr; xz = nxz; xn = nxn;
        xrow += GG;
        hrow += HH;
    }
}

// ---------------------------------------------------------------------------
// Per (b,j): wj = exp(h_alpha . Wa + ba) * M;  val[e] = tanh(h_beta . Wb[e] + bb[e]) * emb[e] * wj
// Grid: B*S blocks x 128 threads (thread = e).
// ---------------------------------------------------------------------------
__global__ __launch_bounds__(128) void attn_val_kernel(
    const float* __restrict__ h_alpha, const float* __restrict__ h_beta,
    const float* __restrict__ emb, const float* __restrict__ M,
    const float* __restrict__ Wa, const float* __restrict__ ba,
    const float* __restrict__ Wb, const float* __restrict__ bb,
    float* __restrict__ val, float* __restrict__ wj)
{
    const int bj = blockIdx.x;       // 0..B*S-1
    const int t = threadIdx.x;       // 0..127
    __shared__ float hb_s[HH];
    __shared__ float wj_s;

    if (t < 64) {
        hb_s[t] = h_beta[(size_t)bj * HH + t];
        float p = h_alpha[(size_t)bj * HH + t] * Wa[t];
        #pragma unroll
        for (int off = 32; off > 0; off >>= 1) p += __shfl_down(p, off);
        if (t == 0) {
            float a = __expf(p + ba[0]) * M[bj];
            wj_s = a;
            wj[bj] = a;
        }
    }
    __syncthreads();

    float acc = bb[t];
    const float4* wrow = (const float4*)&Wb[(size_t)t * HH];
    #pragma unroll
    for (int k = 0; k < 16; ++k) {
        float4 w4 = wrow[k];
        float4 h4 = *(const float4*)&hb_s[k * 4];
        acc += w4.x*h4.x + w4.y*h4.y + w4.z*h4.z + w4.w*h4.w;
    }
    float bw = tanh_f(acc);
    val[(size_t)bj * EE + t] = bw * emb[(size_t)bj * EE + t] * wj_s;
}

// ---------------------------------------------------------------------------
// Suffix scan over j: weighted[b,i,e] = (sum_{j>=i} val[b,j,e]) / (sum_{j>=i} wj[b,j] + 1e-10)
// Grid: B blocks x 128 threads (thread = e).
// ---------------------------------------------------------------------------
__global__ __launch_bounds__(128) void scan_kernel(
    const float* __restrict__ val, const float* __restrict__ wj,
    float* __restrict__ wtd)
{
    const int b = blockIdx.x;
    const int t = threadIdx.x;   // e
    float se = 0.f;
    float d = 1e-10f;
    for (int j = SS - 1; j >= 0; --j) {
        size_t idx = ((size_t)(b * SS + j)) * EE + t;
        se += val[idx];
        d += wj[b * SS + j];
        wtd[idx] = se / d;
    }
}

// ---------------------------------------------------------------------------
// all_output[b,s,l] = (weighted[b,s,:] . Wp[l,:] + bp[l]) * M[b,s]
// Block: 32 rows x 8 l = 256 threads. Grid: 4096/32 = 128 blocks.
// ---------------------------------------------------------------------------
__global__ __launch_bounds__(256) void proj_kernel(
    const float* __restrict__ wtd, const float* __restrict__ Wp,
    const float* __restrict__ bp, const float* __restrict__ M,
    float* __restrict__ out)
{
    __shared__ float wt_s[32][132];
    __shared__ float wp_s[8][132];
    const int t = threadIdx.x;
    const int row0 = blockIdx.x * 32;

    {   // stage weighted tile: 32 x 128
        int r = t >> 3;          // 0..31
        int q = t & 7;           // 0..7
        const float* src = &wtd[(size_t)(row0 + r) * EE];
        #pragma unroll
        for (int it = 0; it < 4; ++it) {
            int kk = (q + it * 8) * 4;
            *(float4*)&wt_s[r][kk] = *(const float4*)&src[kk];
        }
    }
    {   // stage Wp: 8 x 128
        int r = t >> 5;          // 0..7
        int q = t & 31;          // 0..31
        *(float4*)&wp_s[r][q * 4] = *(const float4*)&Wp[(size_t)r * EE + q * 4];
    }
    __syncthreads();

    const int r = t >> 3, l = t & 7;
    float acc = 0.f;
    #pragma unroll
    for (int i = 0; i < 32; ++i) {
        float4 a = *(const float4*)&wt_s[r][i * 4];
        float4 w = *(const float4*)&wp_s[l][i * 4];
        acc += a.x*w.x + a.y*w.y + a.z*w.z + a.w*w.w;
    }
    const int row = row0 + r;
    out[(size_t)row * LL + l] = (acc + bp[l]) * M[row];
}

// ---------------------------------------------------------------------------
// cur_output[b,l] = sum_s all_output[b,s,l] * cur_M[b,s]
// Grid: B blocks x 256 threads.
// ---------------------------------------------------------------------------
__global__ __launch_bounds__(256) void cur_kernel(
    const float* __restrict__ out_all, const float* __restrict__ curM,
    float* __restrict__ out_cur)
{
    const int b = blockIdx.x;
    const int t = threadIdx.x;
    const int l = t & 7, c = t >> 3;   // c: 0..31
    float p = 0.f;
    #pragma unroll
    for (int k = 0; k < 8; ++k) {
        int s = c + k * 32;
        p += out_all[((size_t)(b * SS + s)) * LL + l] * curM[b * SS + s];
    }
    __shared__ float red[32][9];
    red[c][l] = p;
    __syncthreads();
    if (t < 8) {
        float sum = 0.f;
        for (int c2 = 0; c2 < 32; ++c2) sum += red[c2][t];
        out_cur[b * LL + t] = sum;
    }
}

// ---------------------------------------------------------------------------
extern "C" void kernel_launch(void* const* d_in, const int* in_sizes, int n_in,
                              void* d_out, int out_size, void* d_ws, size_t ws_size,
                              hipStream_t stream)
{
    const float* X       = (const float*)d_in[0];
    const float* M       = (const float*)d_in[1];
    const float* cur_M   = (const float*)d_in[2];
    const float* W_embed = (const float*)d_in[3];
    const float* b_embed = (const float*)d_in[4];
    const float* Wih_a   = (const float*)d_in[5];
    const float* Whh_a   = (const float*)d_in[6];
    const float* bih_a   = (const float*)d_in[7];
    const float* bhh_a   = (const float*)d_in[8];
    const float* Wih_b   = (const float*)d_in[9];
    const float* Whh_b   = (const float*)d_in[10];
    const float* bih_b   = (const float*)d_in[11];
    const float* bhh_b   = (const float*)d_in[12];
    const float* Wb      = (const float*)d_in[13];
    const float* bb      = (const float*)d_in[14];
    const float* Wa      = (const float*)d_in[15];
    const float* ba      = (const float*)d_in[16];
    const float* Wp      = (const float*)d_in[17];
    const float* bp      = (const float*)d_in[18];
    float* out = (float*)d_out;

    float* ws  = (float*)d_ws;
    float* emb = ws;                          // B*S*E   = 524288
    float* xpa = emb + (size_t)BB*SS*EE;      // B*S*192 = 786432
    float* xpb = xpa + (size_t)BB*SS*GG;
    float* ha  = xpb + (size_t)BB*SS*GG;      // B*S*H
    float* hb  = ha  + (size_t)BB*SS*HH;
    float* val = hb  + (size_t)BB*SS*HH;      // B*S*E
    float* wjv = val + (size_t)BB*SS*EE;      // B*S
    float* wtd = wjv + (size_t)BB*SS;         // B*S*E

    const int ROWS = BB * SS;                 // 4096

    // 1) emb = X @ W_embed^T + b_embed
    gemm_bt<<<dim3(ROWS/32, EE/64), 256, 0, stream>>>(X, W_embed, b_embed, emb, EE, FF);
    // 2) xp_a / xp_b = emb @ Wih^T + bih
    gemm_bt<<<dim3(ROWS/32, GG/64), 256, 0, stream>>>(emb, Wih_a, bih_a, xpa, GG, EE);
    gemm_bt<<<dim3(ROWS/32, GG/64), 256, 0, stream>>>(emb, Wih_b, bih_b, xpb, GG, EE);
    // 3) both GRU scans (32 independent chains, one wave each)
    gru_kernel<<<32, 64, 0, stream>>>(xpa, xpb, Whh_a, bhh_a, Whh_b, bhh_b, ha, hb);
    // 4) attention weights + per-j values
    attn_val_kernel<<<ROWS, 128, 0, stream>>>(ha, hb, emb, M, Wa, ba, Wb, bb, val, wjv);
    // 5) suffix scan -> weighted
    scan_kernel<<<BB, 128, 0, stream>>>(val, wjv, wtd);
    // 6) projection -> all_output
    proj_kernel<<<ROWS/32, 256, 0, stream>>>(wtd, Wp, bp, M, out);
    // 7) cur_output
    cur_kernel<<<BB, 256, 0, stream>>>(out, cur_M, out + (size_t)BB*SS*LL);
}

// Round 3
// 297.979 us; speedup vs baseline: 1.0298x; 1.0298x over previous
//
#include <hip/hip_runtime.h>
#include <math.h>

#define BB 16
#define SS 256
#define FF 512
#define EE 128
#define HH 64
#define GG 192  // 3H
#define LL 8

typedef float f32x16 __attribute__((ext_vector_type(16)));

__device__ __forceinline__ float sigmoid_f(float x) {
    return 1.0f / (1.0f + __expf(-x));
}
__device__ __forceinline__ float tanh_f(float x) {
    // 1 - 2/(1+e^{2x}): saturates cleanly to ±1, no NaN for large |x|
    return 1.0f - 2.0f / (1.0f + __expf(2.0f * x));
}

// ---------------------------------------------------------------------------
// Generic C[m,n] = sum_k A[m,k] * Bm[n,k] + bias[n]
// Tile: 32 rows x 64 cols, K chunks of 64. Block = 256 threads.
// Requires M % 32 == 0, K % 64 == 0. N handled with guards.
// ---------------------------------------------------------------------------
__device__ __forceinline__ void gemm_bt_body(
    const float* __restrict__ A, const float* __restrict__ Bm,
    const float* __restrict__ bias, float* __restrict__ C,
    int N, int K)
{
    __shared__ float As[32][68];
    __shared__ float Bs[64][68];
    const int t = threadIdx.x;
    const int row0 = blockIdx.x * 32;
    const int col0 = blockIdx.y * 64;
    const int tr = t & 7;        // 0..7 row-group
    const int tc = t >> 3;       // 0..31 col-group
    float acc[4][2] = {{0.f,0.f},{0.f,0.f},{0.f,0.f},{0.f,0.f}};

    for (int k0 = 0; k0 < K; k0 += 64) {
        {
            int r = t >> 3;          // 0..31
            int q = t & 7;           // 0..7
            const float* src = &A[(size_t)(row0 + r) * K + k0];
            #pragma unroll
            for (int it = 0; it < 2; ++it) {
                int kk = (q + it * 8) * 4;
                *(float4*)&As[r][kk] = *(const float4*)&src[kk];
            }
        }
        {
            int r = t >> 2;          // 0..63
            int q = t & 3;           // 0..3
            int n = col0 + r;
            #pragma unroll
            for (int it = 0; it < 4; ++it) {
                int kk = (q + it * 4) * 4;
                float4 v = {0.f, 0.f, 0.f, 0.f};
                if (n < N) v = *(const float4*)&Bm[(size_t)n * K + k0 + kk];
                *(float4*)&Bs[r][kk] = v;
            }
        }
        __syncthreads();
        #pragma unroll
        for (int k = 0; k < 64; k += 4) {
            float4 av[4], bv[2];
            #pragma unroll
            for (int i = 0; i < 4; ++i) av[i] = *(const float4*)&As[tr + 8*i][k];
            #pragma unroll
            for (int j = 0; j < 2; ++j) bv[j] = *(const float4*)&Bs[tc + 32*j][k];
            #pragma unroll
            for (int i = 0; i < 4; ++i)
                #pragma unroll
                for (int j = 0; j < 2; ++j)
                    acc[i][j] += av[i].x*bv[j].x + av[i].y*bv[j].y
                               + av[i].z*bv[j].z + av[i].w*bv[j].w;
        }
        __syncthreads();
    }

    #pragma unroll
    for (int i = 0; i < 4; ++i) {
        int r = row0 + tr + 8*i;
        #pragma unroll
        for (int j = 0; j < 2; ++j) {
            int c = col0 + tc + 32*j;
            if (c < N) C[(size_t)r * N + c] = acc[i][j] + bias[c];
        }
    }
}

__global__ __launch_bounds__(256) void gemm_bt(
    const float* __restrict__ A, const float* __restrict__ Bm,
    const float* __restrict__ bias, float* __restrict__ C,
    int N, int K)
{
    gemm_bt_body(A, Bm, bias, C, N, K);
}

// Two GEMMs sharing A, selected by blockIdx.z (saves a launch).
__global__ __launch_bounds__(256) void gemm_bt_dual(
    const float* __restrict__ A,
    const float* __restrict__ B0, const float* __restrict__ bias0, float* __restrict__ C0,
    const float* __restrict__ B1, const float* __restrict__ bias1, float* __restrict__ C1,
    int N, int K)
{
    const float* Bm   = blockIdx.z ? B1    : B0;
    const float* bias = blockIdx.z ? bias1 : bias0;
    float*       C    = blockIdx.z ? C1    : C0;
    gemm_bt_body(A, Bm, bias, C, N, K);
}

// ---------------------------------------------------------------------------
// GRU scan, latency-optimized. ONE WAVE per (batch, which-gru) chain:
// grid 32 blocks x 64 threads. Lane j holds the three Whh rows (j, j+64,
// j+128) as 12 ext_vector f32x16 SSA values (192 VGPRs — cannot be demoted
// to scratch, unlike C arrays whose allocas SROA failed to promote in r1/r2).
// h-broadcast via v_readlane; no LDS, no barriers in the recurrence.
// ---------------------------------------------------------------------------
__global__ __launch_bounds__(64, 1) void gru_kernel(
    const float* __restrict__ xpa, const float* __restrict__ xpb,
    const float* __restrict__ Whh_a, const float* __restrict__ bhh_a,
    const float* __restrict__ Whh_b, const float* __restrict__ bhh_b,
    float* __restrict__ hs_a, float* __restrict__ hs_b)
{
    const int blk = blockIdx.x;      // 0..31
    const int b = blk >> 1;
    const int which = blk & 1;
    const float* xp  = which ? xpb   : xpa;
    const float* Whh = which ? Whh_b : Whh_a;
    const float* bhh = which ? bhh_b : bhh_a;
    float* hs        = which ? hs_b  : hs_a;

    const int j = threadIdx.x;       // 0..63

    const float* rowr = &Whh[(size_t)j * HH];
    const float* rowz = &Whh[(size_t)(j + 64) * HH];
    const float* rown = &Whh[(size_t)(j + 128) * HH];
    f32x16 wr0 = *(const f32x16*)(rowr);
    f32x16 wr1 = *(const f32x16*)(rowr + 16);
    f32x16 wr2 = *(const f32x16*)(rowr + 32);
    f32x16 wr3 = *(const f32x16*)(rowr + 48);
    f32x16 wz0 = *(const f32x16*)(rowz);
    f32x16 wz1 = *(const f32x16*)(rowz + 16);
    f32x16 wz2 = *(const f32x16*)(rowz + 32);
    f32x16 wz3 = *(const f32x16*)(rowz + 48);
    f32x16 wn0 = *(const f32x16*)(rown);
    f32x16 wn1 = *(const f32x16*)(rown + 16);
    f32x16 wn2 = *(const f32x16*)(rown + 32);
    f32x16 wn3 = *(const f32x16*)(rown + 48);

    const float br = bhh[j], bz = bhh[j + 64], bn = bhh[j + 128];

    const float* xrow = xp + (size_t)b * SS * GG;
    float* hrow = hs + (size_t)b * SS * HH;
    float hcur = 0.f;

    // prefetch step 0
    float xr = xrow[j], xz = xrow[j + 64], xn = xrow[j + 128];

#define GRU_CHUNK(WR, WZ, WN, KB)                                              \
    _Pragma("unroll")                                                          \
    for (int kk = 0; kk < 16; ++kk) {                                          \
        float hk = __int_as_float(                                             \
            __builtin_amdgcn_readlane(__float_as_int(hcur), (KB) + kk));       \
        ar = fmaf(WR[kk], hk, ar);                                             \
        az = fmaf(WZ[kk], hk, az);                                             \
        an = fmaf(WN[kk], hk, an);                                             \
    }

    for (int s = 0; s < SS; ++s) {
        // Prefetch next step's xp (last iter reads 192 floats past this xp
        // array; that lands in the adjacent workspace region — safe, unused).
        const float* nx = xrow + GG;
        float nxr = nx[j], nxz = nx[j + 64], nxn = nx[j + 128];

        float ar = br, az = bz, an = bn;
        GRU_CHUNK(wr0, wz0, wn0, 0)
        GRU_CHUNK(wr1, wz1, wn1, 16)
        GRU_CHUNK(wr2, wz2, wn2, 32)
        GRU_CHUNK(wr3, wz3, wn3, 48)

        float r = sigmoid_f(xr + ar);
        float z = sigmoid_f(xz + az);
        float n = tanh_f(xn + r * an);
        hcur = fmaf(z, hcur - n, n);   // (1-z)*n + z*h
        hrow[j] = hcur;

        xr = nxr; xz = nxz; xn = nxn;
        xrow += GG;
        hrow += HH;
    }
#undef GRU_CHUNK
}

// ---------------------------------------------------------------------------
// Per (b,j): wj = exp(h_alpha . Wa + ba) * M;  val[e] = tanh(h_beta . Wb[e] + bb[e]) * emb[e] * wj
// Grid: B*S blocks x 128 threads (thread = e).
// ---------------------------------------------------------------------------
__global__ __launch_bounds__(128) void attn_val_kernel(
    const float* __restrict__ h_alpha, const float* __restrict__ h_beta,
    const float* __restrict__ emb, const float* __restrict__ M,
    const float* __restrict__ Wa, const float* __restrict__ ba,
    const float* __restrict__ Wb, const float* __restrict__ bb,
    float* __restrict__ val, float* __restrict__ wj)
{
    const int bj = blockIdx.x;       // 0..B*S-1
    const int t = threadIdx.x;       // 0..127
    __shared__ float hb_s[HH];
    __shared__ float wj_s;

    if (t < 64) {
        hb_s[t] = h_beta[(size_t)bj * HH + t];
        float p = h_alpha[(size_t)bj * HH + t] * Wa[t];
        #pragma unroll
        for (int off = 32; off > 0; off >>= 1) p += __shfl_down(p, off);
        if (t == 0) {
            float a = __expf(p + ba[0]) * M[bj];
            wj_s = a;
            wj[bj] = a;
        }
    }
    __syncthreads();

    float acc = bb[t];
    const float4* wrow = (const float4*)&Wb[(size_t)t * HH];
    #pragma unroll
    for (int k = 0; k < 16; ++k) {
        float4 w4 = wrow[k];
        float4 h4 = *(const float4*)&hb_s[k * 4];
        acc += w4.x*h4.x + w4.y*h4.y + w4.z*h4.z + w4.w*h4.w;
    }
    float bw = tanh_f(acc);
    val[(size_t)bj * EE + t] = bw * emb[(size_t)bj * EE + t] * wj_s;
}

// ---------------------------------------------------------------------------
// Suffix scan over j: weighted[b,i,e] = (sum_{j>=i} val[b,j,e]) / (sum_{j>=i} wj[b,j] + 1e-10)
// Grid: B blocks x 128 threads (thread = e).
// ---------------------------------------------------------------------------
__global__ __launch_bounds__(128) void scan_kernel(
    const float* __restrict__ val, const float* __restrict__ wj,
    float* __restrict__ wtd)
{
    const int b = blockIdx.x;
    const int t = threadIdx.x;   // e
    float se = 0.f;
    float d = 1e-10f;
    for (int j = SS - 1; j >= 0; --j) {
        size_t idx = ((size_t)(b * SS + j)) * EE + t;
        se += val[idx];
        d += wj[b * SS + j];
        wtd[idx] = se / d;
    }
}

// ---------------------------------------------------------------------------
// all_output[b,s,l] = (weighted[b,s,:] . Wp[l,:] + bp[l]) * M[b,s]
// Block: 32 rows x 8 l = 256 threads. Grid: 4096/32 = 128 blocks.
// ---------------------------------------------------------------------------
__global__ __launch_bounds__(256) void proj_kernel(
    const float* __restrict__ wtd, const float* __restrict__ Wp,
    const float* __restrict__ bp, const float* __restrict__ M,
    float* __restrict__ out)
{
    __shared__ float wt_s[32][132];
    __shared__ float wp_s[8][132];
    const int t = threadIdx.x;
    const int row0 = blockIdx.x * 32;

    {   // stage weighted tile: 32 x 128
        int r = t >> 3;          // 0..31
        int q = t & 7;           // 0..7
        const float* src = &wtd[(size_t)(row0 + r) * EE];
        #pragma unroll
        for (int it = 0; it < 4; ++it) {
            int kk = (q + it * 8) * 4;
            *(float4*)&wt_s[r][kk] = *(const float4*)&src[kk];
        }
    }
    {   // stage Wp: 8 x 128
        int r = t >> 5;          // 0..7
        int q = t & 31;          // 0..31
        *(float4*)&wp_s[r][q * 4] = *(const float4*)&Wp[(size_t)r * EE + q * 4];
    }
    __syncthreads();

    const int r = t >> 3, l = t & 7;
    float acc = 0.f;
    #pragma unroll
    for (int i = 0; i < 32; ++i) {
        float4 a = *(const float4*)&wt_s[r][i * 4];
        float4 w = *(const float4*)&wp_s[l][i * 4];
        acc += a.x*w.x + a.y*w.y + a.z*w.z + a.w*w.w;
    }
    const int row = row0 + r;
    out[(size_t)row * LL + l] = (acc + bp[l]) * M[row];
}

// ---------------------------------------------------------------------------
// cur_output[b,l] = sum_s all_output[b,s,l] * cur_M[b,s]
// Grid: B blocks x 256 threads.
// ---------------------------------------------------------------------------
__global__ __launch_bounds__(256) void cur_kernel(
    const float* __restrict__ out_all, const float* __restrict__ curM,
    float* __restrict__ out_cur)
{
    const int b = blockIdx.x;
    const int t = threadIdx.x;
    const int l = t & 7, c = t >> 3;   // c: 0..31
    float p = 0.f;
    #pragma unroll
    for (int k = 0; k < 8; ++k) {
        int s = c + k * 32;
        p += out_all[((size_t)(b * SS + s)) * LL + l] * curM[b * SS + s];
    }
    __shared__ float red[32][9];
    red[c][l] = p;
    __syncthreads();
    if (t < 8) {
        float sum = 0.f;
        for (int c2 = 0; c2 < 32; ++c2) sum += red[c2][t];
        out_cur[b * LL + t] = sum;
    }
}

// ---------------------------------------------------------------------------
extern "C" void kernel_launch(void* const* d_in, const int* in_sizes, int n_in,
                              void* d_out, int out_size, void* d_ws, size_t ws_size,
                              hipStream_t stream)
{
    const float* X       = (const float*)d_in[0];
    const float* M       = (const float*)d_in[1];
    const float* cur_M   = (const float*)d_in[2];
    const float* W_embed = (const float*)d_in[3];
    const float* b_embed = (const float*)d_in[4];
    const float* Wih_a   = (const float*)d_in[5];
    const float* Whh_a   = (const float*)d_in[6];
    const float* bih_a   = (const float*)d_in[7];
    const float* bhh_a   = (const float*)d_in[8];
    const float* Wih_b   = (const float*)d_in[9];
    const float* Whh_b   = (const float*)d_in[10];
    const float* bih_b   = (const float*)d_in[11];
    const float* bhh_b   = (const float*)d_in[12];
    const float* Wb      = (const float*)d_in[13];
    const float* bb      = (const float*)d_in[14];
    const float* Wa      = (const float*)d_in[15];
    const float* ba      = (const float*)d_in[16];
    const float* Wp      = (const float*)d_in[17];
    const float* bp      = (const float*)d_in[18];
    float* out = (float*)d_out;

    float* ws  = (float*)d_ws;
    float* emb = ws;                          // B*S*E   = 524288
    float* xpa = emb + (size_t)BB*SS*EE;      // B*S*192 = 786432
    float* xpb = xpa + (size_t)BB*SS*GG;
    float* ha  = xpb + (size_t)BB*SS*GG;      // B*S*H
    float* hb  = ha  + (size_t)BB*SS*HH;
    float* val = hb  + (size_t)BB*SS*HH;      // B*S*E
    float* wjv = val + (size_t)BB*SS*EE;      // B*S
    float* wtd = wjv + (size_t)BB*SS;         // B*S*E

    const int ROWS = BB * SS;                 // 4096

    // 1) emb = X @ W_embed^T + b_embed
    gemm_bt<<<dim3(ROWS/32, EE/64), 256, 0, stream>>>(X, W_embed, b_embed, emb, EE, FF);
    // 2) xp_a / xp_b = emb @ Wih^T + bih  (one dual launch, z selects GRU)
    gemm_bt_dual<<<dim3(ROWS/32, (GG+63)/64, 2), 256, 0, stream>>>(
        emb, Wih_a, bih_a, xpa, Wih_b, bih_b, xpb, GG, EE);
    // 3) both GRU scans (32 independent chains, one wave each)
    gru_kernel<<<32, 64, 0, stream>>>(xpa, xpb, Whh_a, bhh_a, Whh_b, bhh_b, ha, hb);
    // 4) attention weights + per-j values
    attn_val_kernel<<<ROWS, 128, 0, stream>>>(ha, hb, emb, M, Wa, ba, Wb, bb, val, wjv);
    // 5) suffix scan -> weighted
    scan_kernel<<<BB, 128, 0, stream>>>(val, wjv, wtd);
    // 6) projection -> all_output
    proj_kernel<<<ROWS/32, 256, 0, stream>>>(wtd, Wp, bp, M, out);
    // 7) cur_output
    cur_kernel<<<BB, 256, 0, stream>>>(out, cur_M, out + (size_t)BB*SS*LL);
}

// Round 4
// 292.969 us; speedup vs baseline: 1.0474x; 1.0171x over previous
//
#include <hip/hip_runtime.h>
#include <math.h>

#define BB 16
#define SS 256
#define FF 512
#define EE 128
#define HH 64
#define GG 192  // 3H
#define LL 8

typedef float f32x16 __attribute__((ext_vector_type(16)));

__device__ __forceinline__ float sigmoid_f(float x) {
    return 1.0f / (1.0f + __expf(-x));
}
__device__ __forceinline__ float tanh_f(float x) {
    // 1 - 2/(1+e^{2x}): saturates cleanly to ±1, no NaN for large |x|
    return 1.0f - 2.0f / (1.0f + __expf(2.0f * x));
}

// ---------------------------------------------------------------------------
// Generic C[m,n] = sum_k A[m,k] * Bm[n,k] + bias[n]
// Tile: 32 rows x 64 cols, K chunks of 64. Block = 256 threads.
// Requires M % 32 == 0, K % 64 == 0. N handled with guards.
// ---------------------------------------------------------------------------
__device__ __forceinline__ void gemm_bt_body(
    const float* __restrict__ A, const float* __restrict__ Bm,
    const float* __restrict__ bias, float* __restrict__ C,
    int N, int K)
{
    __shared__ float As[32][68];
    __shared__ float Bs[64][68];
    const int t = threadIdx.x;
    const int row0 = blockIdx.x * 32;
    const int col0 = blockIdx.y * 64;
    const int tr = t & 7;        // 0..7 row-group
    const int tc = t >> 3;       // 0..31 col-group
    float acc[4][2] = {{0.f,0.f},{0.f,0.f},{0.f,0.f},{0.f,0.f}};

    for (int k0 = 0; k0 < K; k0 += 64) {
        {
            int r = t >> 3;          // 0..31
            int q = t & 7;           // 0..7
            const float* src = &A[(size_t)(row0 + r) * K + k0];
            #pragma unroll
            for (int it = 0; it < 2; ++it) {
                int kk = (q + it * 8) * 4;
                *(float4*)&As[r][kk] = *(const float4*)&src[kk];
            }
        }
        {
            int r = t >> 2;          // 0..63
            int q = t & 3;           // 0..3
            int n = col0 + r;
            #pragma unroll
            for (int it = 0; it < 4; ++it) {
                int kk = (q + it * 4) * 4;
                float4 v = {0.f, 0.f, 0.f, 0.f};
                if (n < N) v = *(const float4*)&Bm[(size_t)n * K + k0 + kk];
                *(float4*)&Bs[r][kk] = v;
            }
        }
        __syncthreads();
        #pragma unroll
        for (int k = 0; k < 64; k += 4) {
            float4 av[4], bv[2];
            #pragma unroll
            for (int i = 0; i < 4; ++i) av[i] = *(const float4*)&As[tr + 8*i][k];
            #pragma unroll
            for (int j = 0; j < 2; ++j) bv[j] = *(const float4*)&Bs[tc + 32*j][k];
            #pragma unroll
            for (int i = 0; i < 4; ++i)
                #pragma unroll
                for (int j = 0; j < 2; ++j)
                    acc[i][j] += av[i].x*bv[j].x + av[i].y*bv[j].y
                               + av[i].z*bv[j].z + av[i].w*bv[j].w;
        }
        __syncthreads();
    }

    #pragma unroll
    for (int i = 0; i < 4; ++i) {
        int r = row0 + tr + 8*i;
        #pragma unroll
        for (int j = 0; j < 2; ++j) {
            int c = col0 + tc + 32*j;
            if (c < N) C[(size_t)r * N + c] = acc[i][j] + bias[c];
        }
    }
}

__global__ __launch_bounds__(256) void gemm_bt(
    const float* __restrict__ A, const float* __restrict__ Bm,
    const float* __restrict__ bias, float* __restrict__ C,
    int N, int K)
{
    gemm_bt_body(A, Bm, bias, C, N, K);
}

// Two GEMMs sharing A, selected by blockIdx.z (saves a launch).
__global__ __launch_bounds__(256) void gemm_bt_dual(
    const float* __restrict__ A,
    const float* __restrict__ B0, const float* __restrict__ bias0, float* __restrict__ C0,
    const float* __restrict__ B1, const float* __restrict__ bias1, float* __restrict__ C1,
    int N, int K)
{
    const float* Bm   = blockIdx.z ? B1    : B0;
    const float* bias = blockIdx.z ? bias1 : bias0;
    float*       C    = blockIdx.z ? C1    : C0;
    gemm_bt_body(A, Bm, bias, C, N, K);
}

// ---------------------------------------------------------------------------
// GRU scan, latency-optimized. ONE WAVE per (batch, which-gru) chain:
// grid 32 blocks x 64 threads. Lane j holds the three Whh rows (j, j+64,
// j+128) as 12 f32x16 SSA values (192 VGPRs). amdgpu_waves_per_eu(1,1) pins
// the allocator budget to 512 VGPRs (1 wave/SIMD) — without it the backend
// targets ~4 waves/SIMD (~128 VGPRs) and spills the weights to scratch,
// which was the r1-r3 bottleneck (VGPR_Count=108, ~1670 stall cyc/step).
// h-broadcast via v_readlane; no LDS, no barriers in the recurrence.
// ---------------------------------------------------------------------------
__global__ __launch_bounds__(64)
__attribute__((amdgpu_waves_per_eu(1, 1)))
void gru_kernel(
    const float* __restrict__ xpa, const float* __restrict__ xpb,
    const float* __restrict__ Whh_a, const float* __restrict__ bhh_a,
    const float* __restrict__ Whh_b, const float* __restrict__ bhh_b,
    float* __restrict__ hs_a, float* __restrict__ hs_b)
{
    const int blk = blockIdx.x;      // 0..31
    const int b = blk >> 1;
    const int which = blk & 1;
    const float* xp  = which ? xpb   : xpa;
    const float* Whh = which ? Whh_b : Whh_a;
    const float* bhh = which ? bhh_b : bhh_a;
    float* hs        = which ? hs_b  : hs_a;

    const int j = threadIdx.x;       // 0..63

    const float* rowr = &Whh[(size_t)j * HH];
    const float* rowz = &Whh[(size_t)(j + 64) * HH];
    const float* rown = &Whh[(size_t)(j + 128) * HH];
    f32x16 wr0 = *(const f32x16*)(rowr);
    f32x16 wr1 = *(const f32x16*)(rowr + 16);
    f32x16 wr2 = *(const f32x16*)(rowr + 32);
    f32x16 wr3 = *(const f32x16*)(rowr + 48);
    f32x16 wz0 = *(const f32x16*)(rowz);
    f32x16 wz1 = *(const f32x16*)(rowz + 16);
    f32x16 wz2 = *(const f32x16*)(rowz + 32);
    f32x16 wz3 = *(const f32x16*)(rowz + 48);
    f32x16 wn0 = *(const f32x16*)(rown);
    f32x16 wn1 = *(const f32x16*)(rown + 16);
    f32x16 wn2 = *(const f32x16*)(rown + 32);
    f32x16 wn3 = *(const f32x16*)(rown + 48);

    const float br = bhh[j], bz = bhh[j + 64], bn = bhh[j + 128];

    const float* xrow = xp + (size_t)b * SS * GG;
    float* hrow = hs + (size_t)b * SS * HH;
    float hcur = 0.f;

    // prefetch step 0
    float xr = xrow[j], xz = xrow[j + 64], xn = xrow[j + 128];

#define GRU_CHUNK(WR, WZ, WN, KB)                                              \
    _Pragma("unroll")                                                          \
    for (int kk = 0; kk < 16; ++kk) {                                          \
        float hk = __int_as_float(                                             \
            __builtin_amdgcn_readlane(__float_as_int(hcur), (KB) + kk));       \
        ar = fmaf(WR[kk], hk, ar);                                             \
        az = fmaf(WZ[kk], hk, az);                                             \
        an = fmaf(WN[kk], hk, an);                                             \
    }

    for (int s = 0; s < SS; ++s) {
        // Prefetch next step's xp (last iter reads 192 floats past this xp
        // array; that lands in the adjacent workspace region — safe, unused).
        const float* nx = xrow + GG;
        float nxr = nx[j], nxz = nx[j + 64], nxn = nx[j + 128];

        float ar = br, az = bz, an = bn;
        GRU_CHUNK(wr0, wz0, wn0, 0)
        GRU_CHUNK(wr1, wz1, wn1, 16)
        GRU_CHUNK(wr2, wz2, wn2, 32)
        GRU_CHUNK(wr3, wz3, wn3, 48)

        float r = sigmoid_f(xr + ar);
        float z = sigmoid_f(xz + az);
        float n = tanh_f(xn + r * an);
        hcur = fmaf(z, hcur - n, n);   // (1-z)*n + z*h
        hrow[j] = hcur;

        xr = nxr; xz = nxz; xn = nxn;
        xrow += GG;
        hrow += HH;
    }
#undef GRU_CHUNK
}

// ---------------------------------------------------------------------------
// Per (b,j): wj = exp(h_alpha . Wa + ba) * M;  val[e] = tanh(h_beta . Wb[e] + bb[e]) * emb[e] * wj
// Grid: B*S blocks x 128 threads (thread = e).
// ---------------------------------------------------------------------------
__global__ __launch_bounds__(128) void attn_val_kernel(
    const float* __restrict__ h_alpha, const float* __restrict__ h_beta,
    const float* __restrict__ emb, const float* __restrict__ M,
    const float* __restrict__ Wa, const float* __restrict__ ba,
    const float* __restrict__ Wb, const float* __restrict__ bb,
    float* __restrict__ val, float* __restrict__ wj)
{
    const int bj = blockIdx.x;       // 0..B*S-1
    const int t = threadIdx.x;       // 0..127
    __shared__ float hb_s[HH];
    __shared__ float wj_s;

    if (t < 64) {
        hb_s[t] = h_beta[(size_t)bj * HH + t];
        float p = h_alpha[(size_t)bj * HH + t] * Wa[t];
        #pragma unroll
        for (int off = 32; off > 0; off >>= 1) p += __shfl_down(p, off);
        if (t == 0) {
            float a = __expf(p + ba[0]) * M[bj];
            wj_s = a;
            wj[bj] = a;
        }
    }
    __syncthreads();

    float acc = bb[t];
    const float4* wrow = (const float4*)&Wb[(size_t)t * HH];
    #pragma unroll
    for (int k = 0; k < 16; ++k) {
        float4 w4 = wrow[k];
        float4 h4 = *(const float4*)&hb_s[k * 4];
        acc += w4.x*h4.x + w4.y*h4.y + w4.z*h4.z + w4.w*h4.w;
    }
    float bw = tanh_f(acc);
    val[(size_t)bj * EE + t] = bw * emb[(size_t)bj * EE + t] * wj_s;
}

// ---------------------------------------------------------------------------
// Suffix scan over j: weighted[b,i,e] = (sum_{j>=i} val[b,j,e]) / (sum_{j>=i} wj[b,j] + 1e-10)
// Grid: B blocks x 128 threads (thread = e).
// ---------------------------------------------------------------------------
__global__ __launch_bounds__(128) void scan_kernel(
    const float* __restrict__ val, const float* __restrict__ wj,
    float* __restrict__ wtd)
{
    const int b = blockIdx.x;
    const int t = threadIdx.x;   // e
    float se = 0.f;
    float d = 1e-10f;
    for (int j = SS - 1; j >= 0; --j) {
        size_t idx = ((size_t)(b * SS + j)) * EE + t;
        se += val[idx];
        d += wj[b * SS + j];
        wtd[idx] = se / d;
    }
}

// ---------------------------------------------------------------------------
// all_output[b,s,l] = (weighted[b,s,:] . Wp[l,:] + bp[l]) * M[b,s]
// Block: 32 rows x 8 l = 256 threads. Grid: 4096/32 = 128 blocks.
// ---------------------------------------------------------------------------
__global__ __launch_bounds__(256) void proj_kernel(
    const float* __restrict__ wtd, const float* __restrict__ Wp,
    const float* __restrict__ bp, const float* __restrict__ M,
    float* __restrict__ out)
{
    __shared__ float wt_s[32][132];
    __shared__ float wp_s[8][132];
    const int t = threadIdx.x;
    const int row0 = blockIdx.x * 32;

    {   // stage weighted tile: 32 x 128
        int r = t >> 3;          // 0..31
        int q = t & 7;           // 0..7
        const float* src = &wtd[(size_t)(row0 + r) * EE];
        #pragma unroll
        for (int it = 0; it < 4; ++it) {
            int kk = (q + it * 8) * 4;
            *(float4*)&wt_s[r][kk] = *(const float4*)&src[kk];
        }
    }
    {   // stage Wp: 8 x 128
        int r = t >> 5;          // 0..7
        int q = t & 31;          // 0..31
        *(float4*)&wp_s[r][q * 4] = *(const float4*)&Wp[(size_t)r * EE + q * 4];
    }
    __syncthreads();

    const int r = t >> 3, l = t & 7;
    float acc = 0.f;
    #pragma unroll
    for (int i = 0; i < 32; ++i) {
        float4 a = *(const float4*)&wt_s[r][i * 4];
        float4 w = *(const float4*)&wp_s[l][i * 4];
        acc += a.x*w.x + a.y*w.y + a.z*w.z + a.w*w.w;
    }
    const int row = row0 + r;
    out[(size_t)row * LL + l] = (acc + bp[l]) * M[row];
}

// ---------------------------------------------------------------------------
// cur_output[b,l] = sum_s all_output[b,s,l] * cur_M[b,s]
// Grid: B blocks x 256 threads.
// ---------------------------------------------------------------------------
__global__ __launch_bounds__(256) void cur_kernel(
    const float* __restrict__ out_all, const float* __restrict__ curM,
    float* __restrict__ out_cur)
{
    const int b = blockIdx.x;
    const int t = threadIdx.x;
    const int l = t & 7, c = t >> 3;   // c: 0..31
    float p = 0.f;
    #pragma unroll
    for (int k = 0; k < 8; ++k) {
        int s = c + k * 32;
        p += out_all[((size_t)(b * SS + s)) * LL + l] * curM[b * SS + s];
    }
    __shared__ float red[32][9];
    red[c][l] = p;
    __syncthreads();
    if (t < 8) {
        float sum = 0.f;
        for (int c2 = 0; c2 < 32; ++c2) sum += red[c2][t];
        out_cur[b * LL + t] = sum;
    }
}

// ---------------------------------------------------------------------------
extern "C" void kernel_launch(void* const* d_in, const int* in_sizes, int n_in,
                              void* d_out, int out_size, void* d_ws, size_t ws_size,
                              hipStream_t stream)
{
    const float* X       = (const float*)d_in[0];
    const float* M       = (const float*)d_in[1];
    const float* cur_M   = (const float*)d_in[2];
    const float* W_embed = (const float*)d_in[3];
    const float* b_embed = (const float*)d_in[4];
    const float* Wih_a   = (const float*)d_in[5];
    const float* Whh_a   = (const float*)d_in[6];
    const float* bih_a   = (const float*)d_in[7];
    const float* bhh_a   = (const float*)d_in[8];
    const float* Wih_b   = (const float*)d_in[9];
    const float* Whh_b   = (const float*)d_in[10];
    const float* bih_b   = (const float*)d_in[11];
    const float* bhh_b   = (const float*)d_in[12];
    const float* Wb      = (const float*)d_in[13];
    const float* bb      = (const float*)d_in[14];
    const float* Wa      = (const float*)d_in[15];
    const float* ba      = (const float*)d_in[16];
    const float* Wp      = (const float*)d_in[17];
    const float* bp      = (const float*)d_in[18];
    float* out = (float*)d_out;

    float* ws  = (float*)d_ws;
    float* emb = ws;                          // B*S*E   = 524288
    float* xpa = emb + (size_t)BB*SS*EE;      // B*S*192 = 786432
    float* xpb = xpa + (size_t)BB*SS*GG;
    float* ha  = xpb + (size_t)BB*SS*GG;      // B*S*H
    float* hb  = ha  + (size_t)BB*SS*HH;
    float* val = hb  + (size_t)BB*SS*HH;      // B*S*E
    float* wjv = val + (size_t)BB*SS*EE;      // B*S
    float* wtd = wjv + (size_t)BB*SS;         // B*S*E

    const int ROWS = BB * SS;                 // 4096

    // 1) emb = X @ W_embed^T + b_embed
    gemm_bt<<<dim3(ROWS/32, EE/64), 256, 0, stream>>>(X, W_embed, b_embed, emb, EE, FF);
    // 2) xp_a / xp_b = emb @ Wih^T + bih  (one dual launch, z selects GRU)
    gemm_bt_dual<<<dim3(ROWS/32, (GG+63)/64, 2), 256, 0, stream>>>(
        emb, Wih_a, bih_a, xpa, Wih_b, bih_b, xpb, GG, EE);
    // 3) both GRU scans (32 independent chains, one wave each)
    gru_kernel<<<32, 64, 0, stream>>>(xpa, xpb, Whh_a, bhh_a, Whh_b, bhh_b, ha, hb);
    // 4) attention weights + per-j values
    attn_val_kernel<<<ROWS, 128, 0, stream>>>(ha, hb, emb, M, Wa, ba, Wb, bb, val, wjv);
    // 5) suffix scan -> weighted
    scan_kernel<<<BB, 128, 0, stream>>>(val, wjv, wtd);
    // 6) projection -> all_output
    proj_kernel<<<ROWS/32, 256, 0, stream>>>(wtd, Wp, bp, M, out);
    // 7) cur_output
    cur_kernel<<<BB, 256, 0, stream>>>(out, cur_M, out + (size_t)BB*SS*LL);
}

// Round 5
// 214.278 us; speedup vs baseline: 1.4320x; 1.3672x over previous
//
#include <hip/hip_runtime.h>
#include <math.h>

#define BB 16
#define SS 256
#define FF 512
#define EE 128
#define HH 64
#define GG 192  // 3H
#define LL 8

__device__ __forceinline__ float sigmoid_f(float x) {
    return 1.0f / (1.0f + __expf(-x));
}
__device__ __forceinline__ float tanh_f(float x) {
    // 1 - 2/(1+e^{2x}): saturates cleanly to ±1, no NaN for large |x|
    return 1.0f - 2.0f / (1.0f + __expf(2.0f * x));
}

// ---------------------------------------------------------------------------
// Generic C[m,n] = sum_k A[m,k] * Bm[n,k] + bias[n]
// Tile: 32 rows x 64 cols, K chunks of 64. Block = 256 threads.
// Requires M % 32 == 0, K % 64 == 0. N handled with guards.
// ---------------------------------------------------------------------------
__device__ __forceinline__ void gemm_bt_body(
    const float* __restrict__ A, const float* __restrict__ Bm,
    const float* __restrict__ bias, float* __restrict__ C,
    int N, int K)
{
    __shared__ float As[32][68];
    __shared__ float Bs[64][68];
    const int t = threadIdx.x;
    const int row0 = blockIdx.x * 32;
    const int col0 = blockIdx.y * 64;
    const int tr = t & 7;        // 0..7 row-group
    const int tc = t >> 3;       // 0..31 col-group
    float acc[4][2] = {{0.f,0.f},{0.f,0.f},{0.f,0.f},{0.f,0.f}};

    for (int k0 = 0; k0 < K; k0 += 64) {
        {
            int r = t >> 3;          // 0..31
            int q = t & 7;           // 0..7
            const float* src = &A[(size_t)(row0 + r) * K + k0];
            #pragma unroll
            for (int it = 0; it < 2; ++it) {
                int kk = (q + it * 8) * 4;
                *(float4*)&As[r][kk] = *(const float4*)&src[kk];
            }
        }
        {
            int r = t >> 2;          // 0..63
            int q = t & 3;           // 0..3
            int n = col0 + r;
            #pragma unroll
            for (int it = 0; it < 4; ++it) {
                int kk = (q + it * 4) * 4;
                float4 v = {0.f, 0.f, 0.f, 0.f};
                if (n < N) v = *(const float4*)&Bm[(size_t)n * K + k0 + kk];
                *(float4*)&Bs[r][kk] = v;
            }
        }
        __syncthreads();
        #pragma unroll
        for (int k = 0; k < 64; k += 4) {
            float4 av[4], bv[2];
            #pragma unroll
            for (int i = 0; i < 4; ++i) av[i] = *(const float4*)&As[tr + 8*i][k];
            #pragma unroll
            for (int j = 0; j < 2; ++j) bv[j] = *(const float4*)&Bs[tc + 32*j][k];
            #pragma unroll
            for (int i = 0; i < 4; ++i)
                #pragma unroll
                for (int j = 0; j < 2; ++j)
                    acc[i][j] += av[i].x*bv[j].x + av[i].y*bv[j].y
                               + av[i].z*bv[j].z + av[i].w*bv[j].w;
        }
        __syncthreads();
    }

    #pragma unroll
    for (int i = 0; i < 4; ++i) {
        int r = row0 + tr + 8*i;
        #pragma unroll
        for (int j = 0; j < 2; ++j) {
            int c = col0 + tc + 32*j;
            if (c < N) C[(size_t)r * N + c] = acc[i][j] + bias[c];
        }
    }
}

__global__ __launch_bounds__(256) void gemm_bt(
    const float* __restrict__ A, const float* __restrict__ Bm,
    const float* __restrict__ bias, float* __restrict__ C,
    int N, int K)
{
    gemm_bt_body(A, Bm, bias, C, N, K);
}

// Two GEMMs sharing A, selected by blockIdx.z (saves a launch).
__global__ __launch_bounds__(256) void gemm_bt_dual(
    const float* __restrict__ A,
    const float* __restrict__ B0, const float* __restrict__ bias0, float* __restrict__ C0,
    const float* __restrict__ B1, const float* __restrict__ bias1, float* __restrict__ C1,
    int N, int K)
{
    const float* Bm   = blockIdx.z ? B1    : B0;
    const float* bias = blockIdx.z ? bias1 : bias0;
    float*       C    = blockIdx.z ? C1    : C0;
    gemm_bt_body(A, Bm, bias, C, N, K);
}

// ---------------------------------------------------------------------------
// GRU scan, spill-proof variant. One chain per block, THREE waves per block
// (one gate per wave): grid 32 x 192 threads. Lane (g,j) holds ONLY row
// g*64+j of Whh = 64 floats as 16 float4 (4-wide tuples, ~90 VGPR total —
// fits any allocator budget; the r1-r4 designs demanded 192+ weight VGPRs
// and were silently spill-reload-bound at ~1900 cyc/step, VGPR_Count 60-132).
// All 3 waves keep h[j] redundantly in a lane register (identical fp ops ->
// identical values), so the matvec h-broadcast stays readlane-only.
// Gates r,z fold their xp term into the LDS write; n's xp stays outside
// (n = tanh(xn + r*(Wn h + bn))). One barrier/step via double-buffered gh.
// ---------------------------------------------------------------------------
__global__ __launch_bounds__(192, 1)
__attribute__((amdgpu_waves_per_eu(1, 1)))
void gru_kernel(
    const float* __restrict__ xpa, const float* __restrict__ xpb,
    const float* __restrict__ Whh_a, const float* __restrict__ bhh_a,
    const float* __restrict__ Whh_b, const float* __restrict__ bhh_b,
    float* __restrict__ hs_a, float* __restrict__ hs_b)
{
    const int blk = blockIdx.x;      // 0..31
    const int b = blk >> 1;
    const int which = blk & 1;
    const float* xp  = which ? xpb   : xpa;
    const float* Whh = which ? Whh_b : Whh_a;
    const float* bhh = which ? bhh_b : bhh_a;
    float* hs        = which ? hs_b  : hs_a;

    const int t = threadIdx.x;       // 0..191
    const int g = t >> 6;            // gate: 0=r, 1=z, 2=n
    const int j = t & 63;            // lane

    __shared__ float gh_s[2][GG];

    // 64 weights of row g*64+j, as float4s (constant indices after unroll).
    float4 w[16];
    {
        const float4* wrow = (const float4*)&Whh[(size_t)(g * 64 + j) * HH];
        #pragma unroll
        for (int k = 0; k < 16; ++k) w[k] = wrow[k];
    }
    const float bh = bhh[g * 64 + j];

    const float* xrow = xp + (size_t)b * SS * GG;
    float* hrow = hs + (size_t)b * SS * HH;
    float hcur = 0.f;

    // prefetch step 0: own-gate x, plus xn (needed by the h-update)
    float xg = xrow[g * 64 + j];
    float xn = xrow[128 + j];

    for (int s = 0; s < SS; ++s) {
        // Prefetch next step's xp (last iter reads past this xp array into
        // the adjacent workspace region — harmless, value discarded).
        const float* nx = xrow + GG;
        float nxg = nx[g * 64 + j];
        float nxn = nx[128 + j];

        // own-gate dot:  pre = bh + Whh[row] . h   (4 independent chains)
        float a0 = bh, a1 = 0.f, a2 = 0.f, a3 = 0.f;
        #pragma unroll
        for (int kk = 0; kk < 4; ++kk) {
            #pragma unroll
            for (int c = 0; c < 4; ++c) {
                float h0 = __int_as_float(__builtin_amdgcn_readlane(__float_as_int(hcur), 4*kk + c));
                float h1 = __int_as_float(__builtin_amdgcn_readlane(__float_as_int(hcur), 16 + 4*kk + c));
                float h2 = __int_as_float(__builtin_amdgcn_readlane(__float_as_int(hcur), 32 + 4*kk + c));
                float h3 = __int_as_float(__builtin_amdgcn_readlane(__float_as_int(hcur), 48 + 4*kk + c));
                float e0 = (c == 0) ? w[kk].x : (c == 1) ? w[kk].y : (c == 2) ? w[kk].z : w[kk].w;
                float e1 = (c == 0) ? w[4+kk].x : (c == 1) ? w[4+kk].y : (c == 2) ? w[4+kk].z : w[4+kk].w;
                float e2 = (c == 0) ? w[8+kk].x : (c == 1) ? w[8+kk].y : (c == 2) ? w[8+kk].z : w[8+kk].w;
                float e3 = (c == 0) ? w[12+kk].x : (c == 1) ? w[12+kk].y : (c == 2) ? w[12+kk].z : w[12+kk].w;
                a0 = fmaf(e0, h0, a0);
                a1 = fmaf(e1, h1, a1);
                a2 = fmaf(e2, h2, a2);
                a3 = fmaf(e3, h3, a3);
            }
        }
        float pre = (a0 + a1) + (a2 + a3);
        // fold x into r,z pre-activations; n keeps x outside the r* term
        gh_s[s & 1][t] = (g < 2) ? (xg + pre) : pre;
        __syncthreads();

        float ghr = gh_s[s & 1][j];
        float ghz = gh_s[s & 1][64 + j];
        float ghn = gh_s[s & 1][128 + j];
        float r = sigmoid_f(ghr);
        float z = sigmoid_f(ghz);
        float n = tanh_f(xn + r * ghn);
        hcur = fmaf(z, hcur - n, n);   // (1-z)*n + z*h
        if (g == 0) hrow[j] = hcur;

        xg = nxg; xn = nxn;
        xrow += GG;
        hrow += HH;
    }
}

// ---------------------------------------------------------------------------
// Per (b,j): wj = exp(h_alpha . Wa + ba) * M;  val[e] = tanh(h_beta . Wb[e] + bb[e]) * emb[e] * wj
// Grid: B*S blocks x 128 threads (thread = e).
// ---------------------------------------------------------------------------
__global__ __launch_bounds__(128) void attn_val_kernel(
    const float* __restrict__ h_alpha, const float* __restrict__ h_beta,
    const float* __restrict__ emb, const float* __restrict__ M,
    const float* __restrict__ Wa, const float* __restrict__ ba,
    const float* __restrict__ Wb, const float* __restrict__ bb,
    float* __restrict__ val, float* __restrict__ wj)
{
    const int bj = blockIdx.x;       // 0..B*S-1
    const int t = threadIdx.x;       // 0..127
    __shared__ float hb_s[HH];
    __shared__ float wj_s;

    if (t < 64) {
        hb_s[t] = h_beta[(size_t)bj * HH + t];
        float p = h_alpha[(size_t)bj * HH + t] * Wa[t];
        #pragma unroll
        for (int off = 32; off > 0; off >>= 1) p += __shfl_down(p, off);
        if (t == 0) {
            float a = __expf(p + ba[0]) * M[bj];
            wj_s = a;
            wj[bj] = a;
        }
    }
    __syncthreads();

    float acc = bb[t];
    const float4* wrow = (const float4*)&Wb[(size_t)t * HH];
    #pragma unroll
    for (int k = 0; k < 16; ++k) {
        float4 w4 = wrow[k];
        float4 h4 = *(const float4*)&hb_s[k * 4];
        acc += w4.x*h4.x + w4.y*h4.y + w4.z*h4.z + w4.w*h4.w;
    }
    float bw = tanh_f(acc);
    val[(size_t)bj * EE + t] = bw * emb[(size_t)bj * EE + t] * wj_s;
}

// ---------------------------------------------------------------------------
// Suffix scan over j: weighted[b,i,e] = (sum_{j>=i} val[b,j,e]) / (sum_{j>=i} wj[b,j] + 1e-10)
// Grid: B blocks x 128 threads (thread = e).
// ---------------------------------------------------------------------------
__global__ __launch_bounds__(128) void scan_kernel(
    const float* __restrict__ val, const float* __restrict__ wj,
    float* __restrict__ wtd)
{
    const int b = blockIdx.x;
    const int t = threadIdx.x;   // e
    float se = 0.f;
    float d = 1e-10f;
    for (int j = SS - 1; j >= 0; --j) {
        size_t idx = ((size_t)(b * SS + j)) * EE + t;
        se += val[idx];
        d += wj[b * SS + j];
        wtd[idx] = se / d;
    }
}

// ---------------------------------------------------------------------------
// all_output[b,s,l] = (weighted[b,s,:] . Wp[l,:] + bp[l]) * M[b,s]
// Block: 32 rows x 8 l = 256 threads. Grid: 4096/32 = 128 blocks.
// ---------------------------------------------------------------------------
__global__ __launch_bounds__(256) void proj_kernel(
    const float* __restrict__ wtd, const float* __restrict__ Wp,
    const float* __restrict__ bp, const float* __restrict__ M,
    float* __restrict__ out)
{
    __shared__ float wt_s[32][132];
    __shared__ float wp_s[8][132];
    const int t = threadIdx.x;
    const int row0 = blockIdx.x * 32;

    {   // stage weighted tile: 32 x 128
        int r = t >> 3;          // 0..31
        int q = t & 7;           // 0..7
        const float* src = &wtd[(size_t)(row0 + r) * EE];
        #pragma unroll
        for (int it = 0; it < 4; ++it) {
            int kk = (q + it * 8) * 4;
            *(float4*)&wt_s[r][kk] = *(const float4*)&src[kk];
        }
    }
    {   // stage Wp: 8 x 128
        int r = t >> 5;          // 0..7
        int q = t & 31;          // 0..31
        *(float4*)&wp_s[r][q * 4] = *(const float4*)&Wp[(size_t)r * EE + q * 4];
    }
    __syncthreads();

    const int r = t >> 3, l = t & 7;
    float acc = 0.f;
    #pragma unroll
    for (int i = 0; i < 32; ++i) {
        float4 a = *(const float4*)&wt_s[r][i * 4];
        float4 w = *(const float4*)&wp_s[l][i * 4];
        acc += a.x*w.x + a.y*w.y + a.z*w.z + a.w*w.w;
    }
    const int row = row0 + r;
    out[(size_t)row * LL + l] = (acc + bp[l]) * M[row];
}

// ---------------------------------------------------------------------------
// cur_output[b,l] = sum_s all_output[b,s,l] * cur_M[b,s]
// Grid: B blocks x 256 threads.
// ---------------------------------------------------------------------------
__global__ __launch_bounds__(256) void cur_kernel(
    const float* __restrict__ out_all, const float* __restrict__ curM,
    float* __restrict__ out_cur)
{
    const int b = blockIdx.x;
    const int t = threadIdx.x;
    const int l = t & 7, c = t >> 3;   // c: 0..31
    float p = 0.f;
    #pragma unroll
    for (int k = 0; k < 8; ++k) {
        int s = c + k * 32;
        p += out_all[((size_t)(b * SS + s)) * LL + l] * curM[b * SS + s];
    }
    __shared__ float red[32][9];
    red[c][l] = p;
    __syncthreads();
    if (t < 8) {
        float sum = 0.f;
        for (int c2 = 0; c2 < 32; ++c2) sum += red[c2][t];
        out_cur[b * LL + t] = sum;
    }
}

// ---------------------------------------------------------------------------
extern "C" void kernel_launch(void* const* d_in, const int* in_sizes, int n_in,
                              void* d_out, int out_size, void* d_ws, size_t ws_size,
                              hipStream_t stream)
{
    const float* X       = (const float*)d_in[0];
    const float* M       = (const float*)d_in[1];
    const float* cur_M   = (const float*)d_in[2];
    const float* W_embed = (const float*)d_in[3];
    const float* b_embed = (const float*)d_in[4];
    const float* Wih_a   = (const float*)d_in[5];
    const float* Whh_a   = (const float*)d_in[6];
    const float* bih_a   = (const float*)d_in[7];
    const float* bhh_a   = (const float*)d_in[8];
    const float* Wih_b   = (const float*)d_in[9];
    const float* Whh_b   = (const float*)d_in[10];
    const float* bih_b   = (const float*)d_in[11];
    const float* bhh_b   = (const float*)d_in[12];
    const float* Wb      = (const float*)d_in[13];
    const float* bb      = (const float*)d_in[14];
    const float* Wa      = (const float*)d_in[15];
    const float* ba      = (const float*)d_in[16];
    const float* Wp      = (const float*)d_in[17];
    const float* bp      = (const float*)d_in[18];
    float* out = (float*)d_out;

    float* ws  = (float*)d_ws;
    float* emb = ws;                          // B*S*E   = 524288
    float* xpa = emb + (size_t)BB*SS*EE;      // B*S*192 = 786432
    float* xpb = xpa + (size_t)BB*SS*GG;
    float* ha  = xpb + (size_t)BB*SS*GG;      // B*S*H
    float* hb  = ha  + (size_t)BB*SS*HH;
    float* val = hb  + (size_t)BB*SS*HH;      // B*S*E
    float* wjv = val + (size_t)BB*SS*EE;      // B*S
    float* wtd = wjv + (size_t)BB*SS;         // B*S*E

    const int ROWS = BB * SS;                 // 4096

    // 1) emb = X @ W_embed^T + b_embed
    gemm_bt<<<dim3(ROWS/32, EE/64), 256, 0, stream>>>(X, W_embed, b_embed, emb, EE, FF);
    // 2) xp_a / xp_b = emb @ Wih^T + bih  (one dual launch, z selects GRU)
    gemm_bt_dual<<<dim3(ROWS/32, (GG+63)/64, 2), 256, 0, stream>>>(
        emb, Wih_a, bih_a, xpa, Wih_b, bih_b, xpb, GG, EE);
    // 3) both GRU scans (32 chains, 3 waves each — one gate per wave)
    gru_kernel<<<32, 192, 0, stream>>>(xpa, xpb, Whh_a, bhh_a, Whh_b, bhh_b, ha, hb);
    // 4) attention weights + per-j values
    attn_val_kernel<<<ROWS, 128, 0, stream>>>(ha, hb, emb, M, Wa, ba, Wb, bb, val, wjv);
    // 5) suffix scan -> weighted
    scan_kernel<<<BB, 128, 0, stream>>>(val, wjv, wtd);
    // 6) projection -> all_output
    proj_kernel<<<ROWS/32, 256, 0, stream>>>(wtd, Wp, bp, M, out);
    // 7) cur_output
    cur_kernel<<<BB, 256, 0, stream>>>(out, cur_M, out + (size_t)BB*SS*LL);
}

// Round 6
// 202.879 us; speedup vs baseline: 1.5125x; 1.0562x over previous
//
#include <hip/hip_runtime.h>
#include <math.h>

#define BB 16
#define SS 256
#define FF 512
#define EE 128
#define HH 64
#define GG 192  // 3H
#define LL 8

__device__ __forceinline__ float sigmoid_f(float x) {
    return 1.0f / (1.0f + __expf(-x));
}
__device__ __forceinline__ float tanh_f(float x) {
    // 1 - 2/(1+e^{2x}): saturates cleanly to ±1, no NaN for large |x|
    return 1.0f - 2.0f / (1.0f + __expf(2.0f * x));
}

// ---------------------------------------------------------------------------
// Generic C[m,n] = sum_k A[m,k] * Bm[n,k] + bias[n]
// Tile: 32 rows x 64 cols, K chunks of 64. Block = 256 threads.
// Requires M % 32 == 0, K % 64 == 0. N handled with guards.
// ---------------------------------------------------------------------------
__device__ __forceinline__ void gemm_bt_body(
    const float* __restrict__ A, const float* __restrict__ Bm,
    const float* __restrict__ bias, float* __restrict__ C,
    int N, int K)
{
    __shared__ float As[32][68];
    __shared__ float Bs[64][68];
    const int t = threadIdx.x;
    const int row0 = blockIdx.x * 32;
    const int col0 = blockIdx.y * 64;
    const int tr = t & 7;        // 0..7 row-group
    const int tc = t >> 3;       // 0..31 col-group
    float acc[4][2] = {{0.f,0.f},{0.f,0.f},{0.f,0.f},{0.f,0.f}};

    for (int k0 = 0; k0 < K; k0 += 64) {
        {
            int r = t >> 3;          // 0..31
            int q = t & 7;           // 0..7
            const float* src = &A[(size_t)(row0 + r) * K + k0];
            #pragma unroll
            for (int it = 0; it < 2; ++it) {
                int kk = (q + it * 8) * 4;
                *(float4*)&As[r][kk] = *(const float4*)&src[kk];
            }
        }
        {
            int r = t >> 2;          // 0..63
            int q = t & 3;           // 0..3
            int n = col0 + r;
            #pragma unroll
            for (int it = 0; it < 4; ++it) {
                int kk = (q + it * 4) * 4;
                float4 v = {0.f, 0.f, 0.f, 0.f};
                if (n < N) v = *(const float4*)&Bm[(size_t)n * K + k0 + kk];
                *(float4*)&Bs[r][kk] = v;
            }
        }
        __syncthreads();
        #pragma unroll
        for (int k = 0; k < 64; k += 4) {
            float4 av[4], bv[2];
            #pragma unroll
            for (int i = 0; i < 4; ++i) av[i] = *(const float4*)&As[tr + 8*i][k];
            #pragma unroll
            for (int j = 0; j < 2; ++j) bv[j] = *(const float4*)&Bs[tc + 32*j][k];
            #pragma unroll
            for (int i = 0; i < 4; ++i)
                #pragma unroll
                for (int j = 0; j < 2; ++j)
                    acc[i][j] += av[i].x*bv[j].x + av[i].y*bv[j].y
                               + av[i].z*bv[j].z + av[i].w*bv[j].w;
        }
        __syncthreads();
    }

    #pragma unroll
    for (int i = 0; i < 4; ++i) {
        int r = row0 + tr + 8*i;
        #pragma unroll
        for (int j = 0; j < 2; ++j) {
            int c = col0 + tc + 32*j;
            if (c < N) C[(size_t)r * N + c] = acc[i][j] + bias[c];
        }
    }
}

__global__ __launch_bounds__(256) void gemm_bt(
    const float* __restrict__ A, const float* __restrict__ Bm,
    const float* __restrict__ bias, float* __restrict__ C,
    int N, int K)
{
    gemm_bt_body(A, Bm, bias, C, N, K);
}

// Two GEMMs sharing A, selected by blockIdx.z (saves a launch).
__global__ __launch_bounds__(256) void gemm_bt_dual(
    const float* __restrict__ A,
    const float* __restrict__ B0, const float* __restrict__ bias0, float* __restrict__ C0,
    const float* __restrict__ B1, const float* __restrict__ bias1, float* __restrict__ C1,
    int N, int K)
{
    const float* Bm   = blockIdx.z ? B1    : B0;
    const float* bias = blockIdx.z ? bias1 : bias0;
    float*       C    = blockIdx.z ? C1    : C0;
    gemm_bt_body(A, Bm, bias, C, N, K);
}

// ---------------------------------------------------------------------------
// GRU scan. One chain per block, three waves per block (one gate per wave):
// grid 32 x 192. Lane (g,j) holds row g*64+j of Whh = 64 floats in VGPRs.
// KEY FIX (r6): each weight component is routed through an empty
// `asm volatile("" : "+v")` after the load. r2-r5 all reloaded weights every
// step (VGPR_Count 44-132, ~900 stall cyc/step): LLVM RA rematerializes
// loop-invariant loads from __restrict const memory instead of keeping them
// live. An asm result is opaque to remat, so the values must stay in VGPRs
// (~110 live < 128 budget; no occupancy cost at 3 waves/block, 32 blocks).
// h-broadcast via v_readlane; one barrier/step via double-buffered gh.
// ---------------------------------------------------------------------------
__global__ __launch_bounds__(192, 1)
__attribute__((amdgpu_waves_per_eu(1, 1)))
void gru_kernel(
    const float* __restrict__ xpa, const float* __restrict__ xpb,
    const float* __restrict__ Whh_a, const float* __restrict__ bhh_a,
    const float* __restrict__ Whh_b, const float* __restrict__ bhh_b,
    float* __restrict__ hs_a, float* __restrict__ hs_b)
{
    const int blk = blockIdx.x;      // 0..31
    const int b = blk >> 1;
    const int which = blk & 1;
    const float* xp  = which ? xpb   : xpa;
    const float* Whh = which ? Whh_b : Whh_a;
    const float* bhh = which ? bhh_b : bhh_a;
    float* hs        = which ? hs_b  : hs_a;

    const int t = threadIdx.x;       // 0..191
    const int g = t >> 6;            // gate: 0=r, 1=z, 2=n
    const int j = t & 63;            // lane

    __shared__ float gh_s[2][GG];

    // 64 weights of row g*64+j, pinned into VGPRs (see comment above).
    float4 w[16];
    {
        const float4* wrow = (const float4*)&Whh[(size_t)(g * 64 + j) * HH];
        #pragma unroll
        for (int k = 0; k < 16; ++k) {
            w[k] = wrow[k];
            asm volatile("" : "+v"(w[k].x), "+v"(w[k].y), "+v"(w[k].z), "+v"(w[k].w));
        }
    }
    const float bh = bhh[g * 64 + j];

    const float* xrow = xp + (size_t)b * SS * GG;
    float* hrow = hs + (size_t)b * SS * HH;
    float hcur = 0.f;

    // prefetch step 0: own-gate x, plus xn (needed by the h-update)
    float xg = xrow[g * 64 + j];
    float xn = xrow[128 + j];

#define RL(v, k) __int_as_float(__builtin_amdgcn_readlane(__float_as_int(v), (k)))

    for (int s = 0; s < SS; ++s) {
        // Prefetch next step's xp (last iter reads past this xp array into
        // the adjacent workspace region — harmless, value discarded).
        const float* nx = xrow + GG;
        float nxg = nx[g * 64 + j];
        float nxn = nx[128 + j];

        // own-gate dot:  pre = bh + Whh[row] . h   (4 independent chains)
        float a0 = bh, a1 = 0.f, a2 = 0.f, a3 = 0.f;
        #pragma unroll
        for (int k = 0; k < 16; ++k) {
            float4 wk = w[k];
            float h0 = RL(hcur, 4*k + 0);
            float h1 = RL(hcur, 4*k + 1);
            float h2 = RL(hcur, 4*k + 2);
            float h3 = RL(hcur, 4*k + 3);
            a0 = fmaf(wk.x, h0, a0);
            a1 = fmaf(wk.y, h1, a1);
            a2 = fmaf(wk.z, h2, a2);
            a3 = fmaf(wk.w, h3, a3);
        }
        float pre = (a0 + a1) + (a2 + a3);
        // fold x into r,z pre-activations; n keeps x outside the r* term
        gh_s[s & 1][t] = (g < 2) ? (xg + pre) : pre;
        __syncthreads();

        float ghr = gh_s[s & 1][j];
        float ghz = gh_s[s & 1][64 + j];
        float ghn = gh_s[s & 1][128 + j];
        float r = sigmoid_f(ghr);
        float z = sigmoid_f(ghz);
        float n = tanh_f(xn + r * ghn);
        hcur = fmaf(z, hcur - n, n);   // (1-z)*n + z*h
        if (g == 0) hrow[j] = hcur;

        xg = nxg; xn = nxn;
        xrow += GG;
        hrow += HH;
    }
#undef RL
}

// ---------------------------------------------------------------------------
// Per (b,j): wj = exp(h_alpha . Wa + ba) * M;  val[e] = tanh(h_beta . Wb[e] + bb[e]) * emb[e] * wj
// Grid: B*S blocks x 128 threads (thread = e).
// ---------------------------------------------------------------------------
__global__ __launch_bounds__(128) void attn_val_kernel(
    const float* __restrict__ h_alpha, const float* __restrict__ h_beta,
    const float* __restrict__ emb, const float* __restrict__ M,
    const float* __restrict__ Wa, const float* __restrict__ ba,
    const float* __restrict__ Wb, const float* __restrict__ bb,
    float* __restrict__ val, float* __restrict__ wj)
{
    const int bj = blockIdx.x;       // 0..B*S-1
    const int t = threadIdx.x;       // 0..127
    __shared__ float hb_s[HH];
    __shared__ float wj_s;

    if (t < 64) {
        hb_s[t] = h_beta[(size_t)bj * HH + t];
        float p = h_alpha[(size_t)bj * HH + t] * Wa[t];
        #pragma unroll
        for (int off = 32; off > 0; off >>= 1) p += __shfl_down(p, off);
        if (t == 0) {
            float a = __expf(p + ba[0]) * M[bj];
            wj_s = a;
            wj[bj] = a;
        }
    }
    __syncthreads();

    float acc = bb[t];
    const float4* wrow = (const float4*)&Wb[(size_t)t * HH];
    #pragma unroll
    for (int k = 0; k < 16; ++k) {
        float4 w4 = wrow[k];
        float4 h4 = *(const float4*)&hb_s[k * 4];
        acc += w4.x*h4.x + w4.y*h4.y + w4.z*h4.z + w4.w*h4.w;
    }
    float bw = tanh_f(acc);
    val[(size_t)bj * EE + t] = bw * emb[(size_t)bj * EE + t] * wj_s;
}

// ---------------------------------------------------------------------------
// Suffix scan over j: weighted[b,i,e] = (sum_{j>=i} val[b,j,e]) / (sum_{j>=i} wj[b,j] + 1e-10)
// Grid: B blocks x 128 threads (thread = e).
// ---------------------------------------------------------------------------
__global__ __launch_bounds__(128) void scan_kernel(
    const float* __restrict__ val, const float* __restrict__ wj,
    float* __restrict__ wtd)
{
    const int b = blockIdx.x;
    const int t = threadIdx.x;   // e
    float se = 0.f;
    float d = 1e-10f;
    for (int j = SS - 1; j >= 0; --j) {
        size_t idx = ((size_t)(b * SS + j)) * EE + t;
        se += val[idx];
        d += wj[b * SS + j];
        wtd[idx] = se / d;
    }
}

// ---------------------------------------------------------------------------
// all_output[b,s,l] = (weighted[b,s,:] . Wp[l,:] + bp[l]) * M[b,s]
// Block: 32 rows x 8 l = 256 threads. Grid: 4096/32 = 128 blocks.
// ---------------------------------------------------------------------------
__global__ __launch_bounds__(256) void proj_kernel(
    const float* __restrict__ wtd, const float* __restrict__ Wp,
    const float* __restrict__ bp, const float* __restrict__ M,
    float* __restrict__ out)
{
    __shared__ float wt_s[32][132];
    __shared__ float wp_s[8][132];
    const int t = threadIdx.x;
    const int row0 = blockIdx.x * 32;

    {   // stage weighted tile: 32 x 128
        int r = t >> 3;          // 0..31
        int q = t & 7;           // 0..7
        const float* src = &wtd[(size_t)(row0 + r) * EE];
        #pragma unroll
        for (int it = 0; it < 4; ++it) {
            int kk = (q + it * 8) * 4;
            *(float4*)&wt_s[r][kk] = *(const float4*)&src[kk];
        }
    }
    {   // stage Wp: 8 x 128
        int r = t >> 5;          // 0..7
        int q = t & 31;          // 0..31
        *(float4*)&wp_s[r][q * 4] = *(const float4*)&Wp[(size_t)r * EE + q * 4];
    }
    __syncthreads();

    const int r = t >> 3, l = t & 7;
    float acc = 0.f;
    #pragma unroll
    for (int i = 0; i < 32; ++i) {
        float4 a = *(const float4*)&wt_s[r][i * 4];
        float4 w = *(const float4*)&wp_s[l][i * 4];
        acc += a.x*w.x + a.y*w.y + a.z*w.z + a.w*w.w;
    }
    const int row = row0 + r;
    out[(size_t)row * LL + l] = (acc + bp[l]) * M[row];
}

// ---------------------------------------------------------------------------
// cur_output[b,l] = sum_s all_output[b,s,l] * cur_M[b,s]
// Grid: B blocks x 256 threads.
// ---------------------------------------------------------------------------
__global__ __launch_bounds__(256) void cur_kernel(
    const float* __restrict__ out_all, const float* __restrict__ curM,
    float* __restrict__ out_cur)
{
    const int b = blockIdx.x;
    const int t = threadIdx.x;
    const int l = t & 7, c = t >> 3;   // c: 0..31
    float p = 0.f;
    #pragma unroll
    for (int k = 0; k < 8; ++k) {
        int s = c + k * 32;
        p += out_all[((size_t)(b * SS + s)) * LL + l] * curM[b * SS + s];
    }
    __shared__ float red[32][9];
    red[c][l] = p;
    __syncthreads();
    if (t < 8) {
        float sum = 0.f;
        for (int c2 = 0; c2 < 32; ++c2) sum += red[c2][t];
        out_cur[b * LL + t] = sum;
    }
}

// ---------------------------------------------------------------------------
extern "C" void kernel_launch(void* const* d_in, const int* in_sizes, int n_in,
                              void* d_out, int out_size, void* d_ws, size_t ws_size,
                              hipStream_t stream)
{
    const float* X       = (const float*)d_in[0];
    const float* M       = (const float*)d_in[1];
    const float* cur_M   = (const float*)d_in[2];
    const float* W_embed = (const float*)d_in[3];
    const float* b_embed = (const float*)d_in[4];
    const float* Wih_a   = (const float*)d_in[5];
    const float* Whh_a   = (const float*)d_in[6];
    const float* bih_a   = (const float*)d_in[7];
    const float* bhh_a   = (const float*)d_in[8];
    const float* Wih_b   = (const float*)d_in[9];
    const float* Whh_b   = (const float*)d_in[10];
    const float* bih_b   = (const float*)d_in[11];
    const float* bhh_b   = (const float*)d_in[12];
    const float* Wb      = (const float*)d_in[13];
    const float* bb      = (const float*)d_in[14];
    const float* Wa      = (const float*)d_in[15];
    const float* ba      = (const float*)d_in[16];
    const float* Wp      = (const float*)d_in[17];
    const float* bp      = (const float*)d_in[18];
    float* out = (float*)d_out;

    float* ws  = (float*)d_ws;
    float* emb = ws;                          // B*S*E   = 524288
    float* xpa = emb + (size_t)BB*SS*EE;      // B*S*192 = 786432
    float* xpb = xpa + (size_t)BB*SS*GG;
    float* ha  = xpb + (size_t)BB*SS*GG;      // B*S*H
    float* hb  = ha  + (size_t)BB*SS*HH;
    float* val = hb  + (size_t)BB*SS*HH;      // B*S*E
    float* wjv = val + (size_t)BB*SS*EE;      // B*S
    float* wtd = wjv + (size_t)BB*SS;         // B*S*E

    const int ROWS = BB * SS;                 // 4096

    // 1) emb = X @ W_embed^T + b_embed
    gemm_bt<<<dim3(ROWS/32, EE/64), 256, 0, stream>>>(X, W_embed, b_embed, emb, EE, FF);
    // 2) xp_a / xp_b = emb @ Wih^T + bih  (one dual launch, z selects GRU)
    gemm_bt_dual<<<dim3(ROWS/32, (GG+63)/64, 2), 256, 0, stream>>>(
        emb, Wih_a, bih_a, xpa, Wih_b, bih_b, xpb, GG, EE);
    // 3) both GRU scans (32 chains, 3 waves each — one gate per wave)
    gru_kernel<<<32, 192, 0, stream>>>(xpa, xpb, Whh_a, bhh_a, Whh_b, bhh_b, ha, hb);
    // 4) attention weights + per-j values
    attn_val_kernel<<<ROWS, 128, 0, stream>>>(ha, hb, emb, M, Wa, ba, Wb, bb, val, wjv);
    // 5) suffix scan -> weighted
    scan_kernel<<<BB, 128, 0, stream>>>(val, wjv, wtd);
    // 6) projection -> all_output
    proj_kernel<<<ROWS/32, 256, 0, stream>>>(wtd, Wp, bp, M, out);
    // 7) cur_output
    cur_kernel<<<BB, 256, 0, stream>>>(out, cur_M, out + (size_t)BB*SS*LL);
}